// Round 5
// baseline (1347.947 us; speedup 1.0000x reference)
//
#include <hip/hip_runtime.h>
#include <hip/hip_fp16.h>
#include <cstdint>

// Shapes (hard-coded): B=4, Cx=512, Cy=256, M=64, H=W=64, N=4096
constexpr int N_ = 4096;
constexpr float CNT = 16384.f;  // B*N reduction count for BN stats

typedef __attribute__((ext_vector_type(8))) _Float16 half8;
typedef __attribute__((ext_vector_type(4))) float f32x4;
union fragh { half8 h8; int i4[4]; };

__device__ inline int pkh(float a, float b) {
  union { __half2 h; int i; } u;
  u.h = __float22half2_rn(float2{a, b});
  return u.i;
}

// Stats layout (floats): group g in {0:s1,1:x1,2:y1,3:s2,4:x2,5:y2}:
//   sum at g*128+c, sumsq at g*128+64+c (c<64). f_up: sum 768+c, sumsq 1280+c.

// ---------------- stage-1 convs: LDS-staged tile, 32 outputs/thread ----------------
// grid (16 n-slices, 4 b, 6 = branch*2+ogrp). Kills the 16KB-stride latency walk:
// input tile loaded once per chunk with wide coalesced float4, compute is pure VALU.
__global__ __launch_bounds__(256) void conv1_k(
    const float* __restrict__ x, const float* __restrict__ y,
    const float* __restrict__ ws1, const float* __restrict__ wx1,
    const float* __restrict__ wy1,
    float* __restrict__ z1s, float* __restrict__ z1x, float* __restrict__ z1y,
    float* __restrict__ stats) {
  const int t = threadIdx.x;
  const int n0 = blockIdx.x * 256;
  const int b = blockIdx.y;
  const int branch = blockIdx.z >> 1;
  const int o0 = (blockIdx.z & 1) * 32;
  const float* in;
  const float* W;
  float* out;
  int K;
  if (branch == 0) { in = x; W = ws1; out = z1s; K = 512; }
  else if (branch == 1) { in = x; W = wx1; out = z1x; K = 512; }
  else { in = y; W = wy1; out = z1y; K = 256; }
  float* st = stats + branch * 128;

  __shared__ float tile[64 * 256];
  const int w = t >> 6, l = t & 63;

  float acc[32];
#pragma unroll
  for (int o = 0; o < 32; ++o) acc[o] = 0.f;

#pragma unroll 1
  for (int c0 = 0; c0 < K; c0 += 64) {
    __syncthreads();
#pragma unroll
    for (int pass = 0; pass < 16; ++pass) {
      int row = pass * 4 + w;
      float4 v = *(const float4*)&in[((size_t)b * K + c0 + row) * N_ + n0 + l * 4];
      *(float4*)&tile[row * 256 + l * 4] = v;
    }
    __syncthreads();
    float a[64];
#pragma unroll
    for (int c = 0; c < 64; ++c) a[c] = tile[c * 256 + t];
#pragma unroll
    for (int o = 0; o < 32; ++o) {
      const float* wr = W + (size_t)(o0 + o) * K + c0;
      float s = acc[o];
#pragma unroll
      for (int c = 0; c < 64; ++c) s += a[c] * wr[c];
      acc[o] = s;
    }
  }
#pragma unroll
  for (int o = 0; o < 32; ++o)
    out[((size_t)b * 64 + o0 + o) * N_ + n0 + t] = acc[o];
#pragma unroll
  for (int o = 0; o < 32; ++o) {
    float s = acc[o], q = acc[o] * acc[o];
#pragma unroll
    for (int d = 1; d < 64; d <<= 1) { s += __shfl_xor(s, d); q += __shfl_xor(q, d); }
    if (l == 0) { atomicAdd(&st[o0 + o], s); atomicAdd(&st[64 + o0 + o], q); }
  }
}

// ---------------- stage-2 convs (K=64), BN1 applied during staging -----------------
__global__ __launch_bounds__(256) void conv2_k(
    const float* __restrict__ z1s, const float* __restrict__ z1x,
    const float* __restrict__ z1y,
    const float* __restrict__ ws2, const float* __restrict__ wx2,
    const float* __restrict__ wy2,
    const float* __restrict__ gs1, const float* __restrict__ bs1,
    const float* __restrict__ gx1, const float* __restrict__ bx1,
    const float* __restrict__ gy1, const float* __restrict__ by1,
    float* __restrict__ z2s, float* __restrict__ z2x, float* __restrict__ z2y,
    float* __restrict__ stats) {
  const int t = threadIdx.x;
  const int n0 = blockIdx.x * 256;
  const int b = blockIdx.y;
  const int branch = blockIdx.z >> 1;
  const int o0 = (blockIdx.z & 1) * 32;
  const float* in = branch == 0 ? z1s : (branch == 1 ? z1x : z1y);
  const float* W = branch == 0 ? ws2 : (branch == 1 ? wx2 : wy2);
  const float* g1 = branch == 0 ? gs1 : (branch == 1 ? gx1 : gy1);
  const float* b1 = branch == 0 ? bs1 : (branch == 1 ? bx1 : by1);
  float* out = branch == 0 ? z2s : (branch == 1 ? z2x : z2y);
  const float* stin = stats + branch * 128;
  float* stout = stats + (3 + branch) * 128;

  __shared__ float tile[64 * 256];
  __shared__ float sc[64], sh[64];
  const int w = t >> 6, l = t & 63;

  if (t < 64) {
    float mean = stin[t] * (1.f / CNT);
    float var = stin[64 + t] * (1.f / CNT) - mean * mean;
    float r = rsqrtf(var + 1e-5f);
    float s = g1[t] * r;
    sc[t] = s;
    sh[t] = b1[t] - mean * s;
  }
  __syncthreads();

#pragma unroll
  for (int pass = 0; pass < 16; ++pass) {
    int row = pass * 4 + w;
    float4 v = *(const float4*)&in[((size_t)b * 64 + row) * N_ + n0 + l * 4];
    float s = sc[row], h = sh[row];
    v.x = v.x * s + h; v.y = v.y * s + h; v.z = v.z * s + h; v.w = v.w * s + h;
    *(float4*)&tile[row * 256 + l * 4] = v;
  }
  __syncthreads();

  float a[64];
#pragma unroll
  for (int c = 0; c < 64; ++c) a[c] = tile[c * 256 + t];
  float acc[32];
#pragma unroll
  for (int o = 0; o < 32; ++o) {
    const float* wr = W + (size_t)(o0 + o) * 64;
    float s = 0.f;
#pragma unroll
    for (int c = 0; c < 64; ++c) s += a[c] * wr[c];
    acc[o] = s;
  }
#pragma unroll
  for (int o = 0; o < 32; ++o)
    out[((size_t)b * 64 + o0 + o) * N_ + n0 + t] = acc[o];
#pragma unroll
  for (int o = 0; o < 32; ++o) {
    float s = acc[o], q = acc[o] * acc[o];
#pragma unroll
    for (int d = 1; d < 64; d <<= 1) { s += __shfl_xor(s, d); q += __shfl_xor(q, d); }
    if (l == 0) { atomicAdd(&stout[o0 + o], s); atomicAdd(&stout[64 + o0 + o], q); }
  }
}

// ---------------- pack Q/K/V to fp16 packed-pair planar with inline stage-2 BN -----
__global__ __launch_bounds__(256) void pack_k(
    const float* __restrict__ z2s, const float* __restrict__ z2x,
    const float* __restrict__ z2y,
    const float* __restrict__ gs2, const float* __restrict__ bs2,
    const float* __restrict__ gx2, const float* __restrict__ bx2,
    const float* __restrict__ gy2, const float* __restrict__ by2,
    int* __restrict__ Qh, int* __restrict__ Kh, int* __restrict__ Vp,
    const float* __restrict__ stats) {
  const int job = blockIdx.z;  // 0: Q<-x2, 1: K<-y2, 2: V<-s2
  const int idx = blockIdx.x * 256 + threadIdx.x;  // 0..524287
  const float* z2 = job == 0 ? z2x : (job == 1 ? z2y : z2s);
  const float* g2 = job == 0 ? gx2 : (job == 1 ? gy2 : gs2);
  const float* b2 = job == 0 ? bx2 : (job == 1 ? by2 : bs2);
  const float* st = stats + (job == 0 ? 4 : (job == 1 ? 5 : 3)) * 128;
  int* outp = job == 0 ? Qh : (job == 1 ? Kh : Vp);

  auto snorm = [&](int c, float& s, float& h) {
    float mean = st[c] * (1.f / CNT);
    float var = st[64 + c] * (1.f / CNT) - mean * mean;
    float r = rsqrtf(var + 1e-5f);
    s = g2[c] * r;
    h = b2[c] - mean * s;
  };
  if (job < 2) {
    int n = idx & 4095, c = (idx >> 12) & 31, b = idx >> 17;
    float s0, h0, s1, h1;
    snorm(2 * c, s0, h0);
    snorm(2 * c + 1, s1, h1);
    float v0 = z2[((size_t)b * 64 + 2 * c) * N_ + n] * s0 + h0;
    float v1 = z2[((size_t)b * 64 + 2 * c + 1) * N_ + n] * s1 + h1;
    outp[idx] = pkh(v0, v1);
  } else {
    int k = idx & 2047, ch = (idx >> 11) & 63, b = idx >> 17;
    float s0, h0;
    snorm(ch, s0, h0);
    float2 v = *(const float2*)&z2[((size_t)b * 64 + ch) * N_ + 2 * k];
    outp[idx] = pkh(v.x * s0 + h0, v.y * s0 + h0);
  }
}

// ---------------- MFMA fp16 flash attention (unchanged from round 4) ---------------
__global__ __launch_bounds__(256) void attn_k(const int* __restrict__ Qh,
                                              const int* __restrict__ Kh,
                                              const int* __restrict__ Vp,
                                              float* __restrict__ fout) {
  const int tid = threadIdx.x;
  const int lane = tid & 63;
  const int wid = tid >> 6;
  const int la = lane & 15;
  const int quad = lane >> 4;
  const int b = blockIdx.x & 3;
  const int qbase = (blockIdx.x >> 2) * 16;
  const int* Qb = Qh + (size_t)b * 32 * N_;
  const int* Kb = Kh + (size_t)b * 32 * N_;
  const int* Vb = Vp + (size_t)b * 64 * 2048;

  __shared__ union USm {
    float P[4][16 * 36];
    struct { float O[4][16][68]; float M[4][16]; float L[4][16]; } e;
  } smu;
  float* myP = smu.P[wid];

  fragh aq[2];
#pragma unroll
  for (int c = 0; c < 2; ++c)
#pragma unroll
    for (int j = 0; j < 4; ++j)
      aq[c].i4[j] = Qb[(size_t)(c * 16 + quad * 4 + j) * N_ + qbase + la];

  f32x4 o[4];
  float mrun[4], lrun[4];
#pragma unroll
  for (int mt = 0; mt < 4; ++mt) o[mt] = f32x4{0.f, 0.f, 0.f, 0.f};
#pragma unroll
  for (int r = 0; r < 4; ++r) { mrun[r] = -3.0e38f; lrun[r] = 0.f; }

  const int jbeg = wid * (N_ / 4);
#pragma unroll 1
  for (int j0 = jbeg; j0 < jbeg + N_ / 4; j0 += 32) {
    f32x4 s[2];
#pragma unroll
    for (int nt = 0; nt < 2; ++nt) {
      fragh k0, k1;
      const int key = j0 + nt * 16 + la;
#pragma unroll
      for (int jj = 0; jj < 4; ++jj) {
        k0.i4[jj] = Kb[(size_t)(quad * 4 + jj) * N_ + key];
        k1.i4[jj] = Kb[(size_t)(16 + quad * 4 + jj) * N_ + key];
      }
      f32x4 z = f32x4{0.f, 0.f, 0.f, 0.f};
      z = __builtin_amdgcn_mfma_f32_16x16x32_f16(aq[0].h8, k0.h8, z, 0, 0, 0);
      s[nt] = __builtin_amdgcn_mfma_f32_16x16x32_f16(aq[1].h8, k1.h8, z, 0, 0, 0);
    }
    float alpha[4];
#pragma unroll
    for (int r = 0; r < 4; ++r) {
      float t = fmaxf(s[0][r], s[1][r]);
      t = fmaxf(t, __shfl_xor(t, 1));
      t = fmaxf(t, __shfl_xor(t, 2));
      t = fmaxf(t, __shfl_xor(t, 4));
      t = fmaxf(t, __shfl_xor(t, 8));
      float mnew = fmaxf(mrun[r], t);
      alpha[r] = __expf(mrun[r] - mnew);
      float p0 = __expf(s[0][r] - mnew);
      float p1 = __expf(s[1][r] - mnew);
      s[0][r] = p0; s[1][r] = p1;
      float ps = p0 + p1;
      ps += __shfl_xor(ps, 1);
      ps += __shfl_xor(ps, 2);
      ps += __shfl_xor(ps, 4);
      ps += __shfl_xor(ps, 8);
      lrun[r] = lrun[r] * alpha[r] + ps;
      mrun[r] = mnew;
    }
#pragma unroll
    for (int nt = 0; nt < 2; ++nt)
#pragma unroll
      for (int r = 0; r < 4; ++r)
        myP[(quad * 4 + r) * 36 + nt * 16 + la] = s[nt][r];
    __asm__ __volatile__("s_waitcnt lgkmcnt(0)" ::: "memory");
    fragh pa;
    {
      const f32x4* pr = (const f32x4*)&myP[la * 36 + quad * 8];
      f32x4 p0 = pr[0], p1 = pr[1];
      pa.i4[0] = pkh(p0[0], p0[1]);
      pa.i4[1] = pkh(p0[2], p0[3]);
      pa.i4[2] = pkh(p1[0], p1[1]);
      pa.i4[3] = pkh(p1[2], p1[3]);
    }
#pragma unroll
    for (int mt = 0; mt < 4; ++mt)
#pragma unroll
      for (int r = 0; r < 4; ++r) o[mt][r] *= alpha[r];
#pragma unroll
    for (int mt = 0; mt < 4; ++mt) {
      const int4 vv = *(const int4*)&Vb[(size_t)(mt * 16 + la) * 2048 + (j0 >> 1) + quad * 4];
      fragh vb;
      vb.i4[0] = vv.x; vb.i4[1] = vv.y; vb.i4[2] = vv.z; vb.i4[3] = vv.w;
      o[mt] = __builtin_amdgcn_mfma_f32_16x16x32_f16(pa.h8, vb.h8, o[mt], 0, 0, 0);
    }
  }

  __syncthreads();
  if (la == 0) {
#pragma unroll
    for (int r = 0; r < 4; ++r) {
      smu.e.M[wid][quad * 4 + r] = mrun[r];
      smu.e.L[wid][quad * 4 + r] = lrun[r];
    }
  }
#pragma unroll
  for (int mt = 0; mt < 4; ++mt)
#pragma unroll
    for (int r = 0; r < 4; ++r) smu.e.O[wid][quad * 4 + r][mt * 16 + la] = o[mt][r];
  __syncthreads();

#pragma unroll
  for (int t = 0; t < 4; ++t) {
    int oidx = t * 256 + tid;
    int m = oidx >> 4;
    int q = oidx & 15;
    float m0 = fmaxf(fmaxf(smu.e.M[0][q], smu.e.M[1][q]),
                     fmaxf(smu.e.M[2][q], smu.e.M[3][q]));
    float num = 0.f, den = 0.f;
#pragma unroll
    for (int w = 0; w < 4; ++w) {
      float wgt = __expf(smu.e.M[w][q] - m0);
      num += wgt * smu.e.O[w][q][m];
      den += wgt * smu.e.L[w][q];
    }
    fout[((size_t)b * 64 + m) * N_ + qbase + q] = num / den;
  }
}

// ---------------- f_up conv (K=64, Ot=512): LDS-staged, 32 outputs/thread ----------
__global__ __launch_bounds__(256) void convup_k(const float* __restrict__ fout,
                                                const float* __restrict__ wu,
                                                float* __restrict__ u,
                                                float* __restrict__ stats) {
  const int t = threadIdx.x;
  const int n0 = blockIdx.x * 256;
  const int b = blockIdx.y;
  const int o0 = blockIdx.z * 32;

  __shared__ float tile[64 * 256];
  const int w = t >> 6, l = t & 63;
#pragma unroll
  for (int pass = 0; pass < 16; ++pass) {
    int row = pass * 4 + w;
    float4 v = *(const float4*)&fout[((size_t)b * 64 + row) * N_ + n0 + l * 4];
    *(float4*)&tile[row * 256 + l * 4] = v;
  }
  __syncthreads();

  float a[64];
#pragma unroll
  for (int c = 0; c < 64; ++c) a[c] = tile[c * 256 + t];
  float acc[32];
#pragma unroll
  for (int o = 0; o < 32; ++o) {
    const float* wr = wu + (size_t)(o0 + o) * 64;
    float s = 0.f;
#pragma unroll
    for (int c = 0; c < 64; ++c) s += a[c] * wr[c];
    acc[o] = s;
  }
#pragma unroll
  for (int o = 0; o < 32; ++o)
    u[((size_t)b * 512 + o0 + o) * N_ + n0 + t] = acc[o];
#pragma unroll
  for (int o = 0; o < 32; ++o) {
    float s = acc[o], q = acc[o] * acc[o];
#pragma unroll
    for (int d = 1; d < 64; d <<= 1) { s += __shfl_xor(s, d); q += __shfl_xor(q, d); }
    if (l == 0) {
      atomicAdd(&stats[768 + o0 + o], s);
      atomicAdd(&stats[1280 + o0 + o], q);
    }
  }
}

// ---------------- residual + final BN ----------------------------------------------
__global__ __launch_bounds__(256) void final_k(const float* __restrict__ x,
                                               const float* __restrict__ u,
                                               const float* __restrict__ gu,
                                               const float* __restrict__ bu,
                                               const float* __restrict__ stats,
                                               float* __restrict__ out) {
  size_t idx = (size_t)blockIdx.x * 256 + threadIdx.x;
  int c = (int)((idx >> 12) & 511);
  float mean = stats[768 + c] * (1.f / CNT);
  float var = stats[1280 + c] * (1.f / CNT) - mean * mean;
  float r = rsqrtf(var + 1e-5f);
  float s = gu[c] * r;
  float sh = bu[c] - mean * s;
  out[idx] = x[idx] + u[idx] * s + sh;
}

extern "C" void kernel_launch(void* const* d_in, const int* in_sizes, int n_in,
                              void* d_out, int out_size, void* d_ws, size_t ws_size,
                              hipStream_t stream) {
  const float* x = (const float*)d_in[0];
  const float* y = (const float*)d_in[1];
  const float* ws1 = (const float*)d_in[2];
  const float* gs1 = (const float*)d_in[3];
  const float* bs1 = (const float*)d_in[4];
  const float* ws2 = (const float*)d_in[5];
  const float* gs2 = (const float*)d_in[6];
  const float* bs2 = (const float*)d_in[7];
  const float* wx1 = (const float*)d_in[8];
  const float* gx1 = (const float*)d_in[9];
  const float* bx1 = (const float*)d_in[10];
  const float* wx2 = (const float*)d_in[11];
  const float* gx2 = (const float*)d_in[12];
  const float* bx2 = (const float*)d_in[13];
  const float* wy1 = (const float*)d_in[14];
  const float* gy1 = (const float*)d_in[15];
  const float* by1 = (const float*)d_in[16];
  const float* wy2 = (const float*)d_in[17];
  const float* gy2 = (const float*)d_in[18];
  const float* by2 = (const float*)d_in[19];
  const float* wu = (const float*)d_in[20];
  const float* gu = (const float*)d_in[21];
  const float* bu = (const float*)d_in[22];
  float* out = (float*)d_out;

  float* w = (float*)d_ws;
  const size_t M1 = 1048576;
  float* z1s = w + 0 * M1;
  float* z1x = w + 1 * M1;
  float* z1y = w + 2 * M1;
  float* z2s = w + 3 * M1;
  float* z2x = w + 4 * M1;
  float* z2y = w + 5 * M1;
  float* fout = w + 6 * M1;
  float* u = w + 7 * M1;             // [4][512][4096] = 8 M floats
  int* Qh = (int*)(w + 15 * M1);
  int* Kh = Qh + 524288;
  int* Vp = Kh + 524288;
  float* stats = (float*)(Vp + 524288);

  hipMemsetAsync(stats, 0, 1792 * sizeof(float), stream);

  conv1_k<<<dim3(16, 4, 6), dim3(256), 0, stream>>>(x, y, ws1, wx1, wy1, z1s, z1x,
                                                    z1y, stats);
  conv2_k<<<dim3(16, 4, 6), dim3(256), 0, stream>>>(
      z1s, z1x, z1y, ws2, wx2, wy2, gs1, bs1, gx1, bx1, gy1, by1, z2s, z2x, z2y,
      stats);
  pack_k<<<dim3(2048, 1, 3), dim3(256), 0, stream>>>(z2s, z2x, z2y, gs2, bs2, gx2,
                                                     bx2, gy2, by2, Qh, Kh, Vp,
                                                     stats);
  attn_k<<<dim3(1024), dim3(256), 0, stream>>>(Qh, Kh, Vp, fout);
  convup_k<<<dim3(16, 4, 16), dim3(256), 0, stream>>>(fout, wu, u, stats);
  final_k<<<dim3(32768), dim3(256), 0, stream>>>(x, u, gu, bu, stats, out);
}

// Round 6
// 407.215 us; speedup vs baseline: 3.3102x; 3.3102x over previous
//
#include <hip/hip_runtime.h>
#include <hip/hip_fp16.h>
#include <cstdint>

// Shapes (hard-coded): B=4, Cx=512, Cy=256, M=64, H=W=64, N=4096
constexpr int N_ = 4096;
constexpr float CNT = 16384.f;  // B*N reduction count for BN stats

typedef __attribute__((ext_vector_type(8))) _Float16 half8;
typedef __attribute__((ext_vector_type(4))) float f32x4;
union fragh { half8 h8; int i4[4]; };

__device__ inline int pkh(float a, float b) {
  union { __half2 h; int i; } u;
  u.h = __float22half2_rn(float2{a, b});
  return u.i;
}

// Stats layout (floats): group g in {0:s1,1:x1,2:y1,3:s2,4:x2,5:y2}:
//   sum at g*128+c, sumsq at g*128+64+c (c<64). f_up: sum 768+c, sumsq 1280+c.

// ---------------- stage-1 convs: SGEMM tiling, 64o x 128n tile, 8x4/thread ---------
// Both A and W staged in LDS; inner loop is pure register outer-product (32 indep
// acc chains) -> no dependent weight-load stalls (round-5 failure mode).
__global__ __launch_bounds__(256) void conv1_k(
    const float* __restrict__ x, const float* __restrict__ y,
    const float* __restrict__ ws1, const float* __restrict__ wx1,
    const float* __restrict__ wy1,
    float* __restrict__ z1s, float* __restrict__ z1x, float* __restrict__ z1y,
    float* __restrict__ stats) {
  const int t = threadIdx.x;
  const int slice = blockIdx.x;  // 0..127
  const int b = slice >> 5;
  const int n0 = (slice & 31) * 128;
  const int branch = blockIdx.y;  // 0:s 1:x 2:y
  const float* A = branch == 2 ? y : x;
  const float* W = branch == 0 ? ws1 : (branch == 1 ? wx1 : wy1);
  float* out = branch == 0 ? z1s : (branch == 1 ? z1x : z1y);
  const int K = branch == 2 ? 256 : 512;
  float* st = stats + branch * 128;

  __shared__ float sA[32][132];
  __shared__ float sW[32][72];

  const int to = (t >> 5) * 8;
  const int tn = (t & 31) * 4;
  float acc[8][4];
#pragma unroll
  for (int i = 0; i < 8; ++i)
#pragma unroll
    for (int j = 0; j < 4; ++j) acc[i][j] = 0.f;

  const float* Ab = A + (size_t)b * K * N_ + n0;
#pragma unroll 1
  for (int k0 = 0; k0 < K; k0 += 32) {
    __syncthreads();
#pragma unroll
    for (int i = 0; i < 4; ++i) {
      int row = i * 8 + (t >> 5);
      float4 v = *(const float4*)&Ab[(size_t)(k0 + row) * N_ + tn];
      *(float4*)&sA[row][tn] = v;
    }
    {
      int o = t >> 2, kk = (t & 3) * 8;
      float4 w0 = *(const float4*)&W[(size_t)o * K + k0 + kk];
      float4 w1 = *(const float4*)&W[(size_t)o * K + k0 + kk + 4];
      sW[kk + 0][o] = w0.x; sW[kk + 1][o] = w0.y;
      sW[kk + 2][o] = w0.z; sW[kk + 3][o] = w0.w;
      sW[kk + 4][o] = w1.x; sW[kk + 5][o] = w1.y;
      sW[kk + 6][o] = w1.z; sW[kk + 7][o] = w1.w;
    }
    __syncthreads();
#pragma unroll
    for (int k = 0; k < 32; ++k) {
      float4 a = *(const float4*)&sA[k][tn];
      float4 w0 = *(const float4*)&sW[k][to];
      float4 w1 = *(const float4*)&sW[k][to + 4];
      float wv[8] = {w0.x, w0.y, w0.z, w0.w, w1.x, w1.y, w1.z, w1.w};
      float av[4] = {a.x, a.y, a.z, a.w};
#pragma unroll
      for (int i = 0; i < 8; ++i)
#pragma unroll
        for (int j = 0; j < 4; ++j) acc[i][j] += wv[i] * av[j];
    }
  }
  float* Cb = out + (size_t)b * 64 * N_ + n0;
#pragma unroll
  for (int i = 0; i < 8; ++i) {
    float4 v = {acc[i][0], acc[i][1], acc[i][2], acc[i][3]};
    *(float4*)&Cb[(size_t)(to + i) * N_ + tn] = v;
  }
#pragma unroll
  for (int i = 0; i < 8; ++i) {
    float s = acc[i][0] + acc[i][1] + acc[i][2] + acc[i][3];
    float q = acc[i][0] * acc[i][0] + acc[i][1] * acc[i][1] +
              acc[i][2] * acc[i][2] + acc[i][3] * acc[i][3];
#pragma unroll
    for (int d = 1; d < 32; d <<= 1) { s += __shfl_xor(s, d); q += __shfl_xor(q, d); }
    if ((t & 31) == 0) { atomicAdd(&st[to + i], s); atomicAdd(&st[64 + to + i], q); }
  }
}

// ---------------- stage-2 convs (K=64), BN1 applied during A staging ---------------
__global__ __launch_bounds__(256) void conv2_k(
    const float* __restrict__ z1s, const float* __restrict__ z1x,
    const float* __restrict__ z1y,
    const float* __restrict__ ws2, const float* __restrict__ wx2,
    const float* __restrict__ wy2,
    const float* __restrict__ gs1, const float* __restrict__ bs1,
    const float* __restrict__ gx1, const float* __restrict__ bx1,
    const float* __restrict__ gy1, const float* __restrict__ by1,
    float* __restrict__ z2s, float* __restrict__ z2x, float* __restrict__ z2y,
    float* __restrict__ stats) {
  const int t = threadIdx.x;
  const int slice = blockIdx.x;
  const int b = slice >> 5;
  const int n0 = (slice & 31) * 128;
  const int branch = blockIdx.y;
  const float* A = branch == 0 ? z1s : (branch == 1 ? z1x : z1y);
  const float* W = branch == 0 ? ws2 : (branch == 1 ? wx2 : wy2);
  const float* g1 = branch == 0 ? gs1 : (branch == 1 ? gx1 : gy1);
  const float* b1 = branch == 0 ? bs1 : (branch == 1 ? bx1 : by1);
  float* out = branch == 0 ? z2s : (branch == 1 ? z2x : z2y);
  const float* stin = stats + branch * 128;
  float* stout = stats + (3 + branch) * 128;

  __shared__ float sA[32][132];
  __shared__ float sW[32][72];
  __shared__ float sc[64], sh[64];

  if (t < 64) {
    float mean = stin[t] * (1.f / CNT);
    float var = stin[64 + t] * (1.f / CNT) - mean * mean;
    float r = rsqrtf(var + 1e-5f);
    float s = g1[t] * r;
    sc[t] = s;
    sh[t] = b1[t] - mean * s;
  }

  const int to = (t >> 5) * 8;
  const int tn = (t & 31) * 4;
  float acc[8][4];
#pragma unroll
  for (int i = 0; i < 8; ++i)
#pragma unroll
    for (int j = 0; j < 4; ++j) acc[i][j] = 0.f;

  const float* Ab = A + (size_t)b * 64 * N_ + n0;
#pragma unroll 1
  for (int k0 = 0; k0 < 64; k0 += 32) {
    __syncthreads();
#pragma unroll
    for (int i = 0; i < 4; ++i) {
      int row = i * 8 + (t >> 5);
      float4 v = *(const float4*)&Ab[(size_t)(k0 + row) * N_ + tn];
      float s = sc[k0 + row], h = sh[k0 + row];
      v.x = v.x * s + h; v.y = v.y * s + h; v.z = v.z * s + h; v.w = v.w * s + h;
      *(float4*)&sA[row][tn] = v;
    }
    {
      int o = t >> 2, kk = (t & 3) * 8;
      float4 w0 = *(const float4*)&W[(size_t)o * 64 + k0 + kk];
      float4 w1 = *(const float4*)&W[(size_t)o * 64 + k0 + kk + 4];
      sW[kk + 0][o] = w0.x; sW[kk + 1][o] = w0.y;
      sW[kk + 2][o] = w0.z; sW[kk + 3][o] = w0.w;
      sW[kk + 4][o] = w1.x; sW[kk + 5][o] = w1.y;
      sW[kk + 6][o] = w1.z; sW[kk + 7][o] = w1.w;
    }
    __syncthreads();
#pragma unroll
    for (int k = 0; k < 32; ++k) {
      float4 a = *(const float4*)&sA[k][tn];
      float4 w0 = *(const float4*)&sW[k][to];
      float4 w1 = *(const float4*)&sW[k][to + 4];
      float wv[8] = {w0.x, w0.y, w0.z, w0.w, w1.x, w1.y, w1.z, w1.w};
      float av[4] = {a.x, a.y, a.z, a.w};
#pragma unroll
      for (int i = 0; i < 8; ++i)
#pragma unroll
        for (int j = 0; j < 4; ++j) acc[i][j] += wv[i] * av[j];
    }
  }
  float* Cb = out + (size_t)b * 64 * N_ + n0;
#pragma unroll
  for (int i = 0; i < 8; ++i) {
    float4 v = {acc[i][0], acc[i][1], acc[i][2], acc[i][3]};
    *(float4*)&Cb[(size_t)(to + i) * N_ + tn] = v;
  }
#pragma unroll
  for (int i = 0; i < 8; ++i) {
    float s = acc[i][0] + acc[i][1] + acc[i][2] + acc[i][3];
    float q = acc[i][0] * acc[i][0] + acc[i][1] * acc[i][1] +
              acc[i][2] * acc[i][2] + acc[i][3] * acc[i][3];
#pragma unroll
    for (int d = 1; d < 32; d <<= 1) { s += __shfl_xor(s, d); q += __shfl_xor(q, d); }
    if ((t & 31) == 0) { atomicAdd(&stout[to + i], s); atomicAdd(&stout[64 + to + i], q); }
  }
}

// ---------------- pack Q/K/V to fp16 packed-pair planar with inline stage-2 BN -----
__global__ __launch_bounds__(256) void pack_k(
    const float* __restrict__ z2s, const float* __restrict__ z2x,
    const float* __restrict__ z2y,
    const float* __restrict__ gs2, const float* __restrict__ bs2,
    const float* __restrict__ gx2, const float* __restrict__ bx2,
    const float* __restrict__ gy2, const float* __restrict__ by2,
    int* __restrict__ Qh, int* __restrict__ Kh, int* __restrict__ Vp,
    const float* __restrict__ stats) {
  const int job = blockIdx.z;  // 0: Q<-x2, 1: K<-y2, 2: V<-s2
  const int idx = blockIdx.x * 256 + threadIdx.x;  // 0..524287
  const float* z2 = job == 0 ? z2x : (job == 1 ? z2y : z2s);
  const float* g2 = job == 0 ? gx2 : (job == 1 ? gy2 : gs2);
  const float* b2 = job == 0 ? bx2 : (job == 1 ? by2 : bs2);
  const float* st = stats + (job == 0 ? 4 : (job == 1 ? 5 : 3)) * 128;
  int* outp = job == 0 ? Qh : (job == 1 ? Kh : Vp);

  auto snorm = [&](int c, float& s, float& h) {
    float mean = st[c] * (1.f / CNT);
    float var = st[64 + c] * (1.f / CNT) - mean * mean;
    float r = rsqrtf(var + 1e-5f);
    s = g2[c] * r;
    h = b2[c] - mean * s;
  };
  if (job < 2) {
    int n = idx & 4095, c = (idx >> 12) & 31, b = idx >> 17;
    float s0, h0, s1, h1;
    snorm(2 * c, s0, h0);
    snorm(2 * c + 1, s1, h1);
    float v0 = z2[((size_t)b * 64 + 2 * c) * N_ + n] * s0 + h0;
    float v1 = z2[((size_t)b * 64 + 2 * c + 1) * N_ + n] * s1 + h1;
    outp[idx] = pkh(v0, v1);
  } else {
    int k = idx & 2047, ch = (idx >> 11) & 63, b = idx >> 17;
    float s0, h0;
    snorm(ch, s0, h0);
    float2 v = *(const float2*)&z2[((size_t)b * 64 + ch) * N_ + 2 * k];
    outp[idx] = pkh(v.x * s0 + h0, v.y * s0 + h0);
  }
}

// ---------------- MFMA fp16 flash attention (unchanged, validated round 4) ---------
__global__ __launch_bounds__(256) void attn_k(const int* __restrict__ Qh,
                                              const int* __restrict__ Kh,
                                              const int* __restrict__ Vp,
                                              float* __restrict__ fout) {
  const int tid = threadIdx.x;
  const int lane = tid & 63;
  const int wid = tid >> 6;
  const int la = lane & 15;
  const int quad = lane >> 4;
  const int b = blockIdx.x & 3;
  const int qbase = (blockIdx.x >> 2) * 16;
  const int* Qb = Qh + (size_t)b * 32 * N_;
  const int* Kb = Kh + (size_t)b * 32 * N_;
  const int* Vb = Vp + (size_t)b * 64 * 2048;

  __shared__ union USm {
    float P[4][16 * 36];
    struct { float O[4][16][68]; float M[4][16]; float L[4][16]; } e;
  } smu;
  float* myP = smu.P[wid];

  fragh aq[2];
#pragma unroll
  for (int c = 0; c < 2; ++c)
#pragma unroll
    for (int j = 0; j < 4; ++j)
      aq[c].i4[j] = Qb[(size_t)(c * 16 + quad * 4 + j) * N_ + qbase + la];

  f32x4 o[4];
  float mrun[4], lrun[4];
#pragma unroll
  for (int mt = 0; mt < 4; ++mt) o[mt] = f32x4{0.f, 0.f, 0.f, 0.f};
#pragma unroll
  for (int r = 0; r < 4; ++r) { mrun[r] = -3.0e38f; lrun[r] = 0.f; }

  const int jbeg = wid * (N_ / 4);
#pragma unroll 1
  for (int j0 = jbeg; j0 < jbeg + N_ / 4; j0 += 32) {
    f32x4 s[2];
#pragma unroll
    for (int nt = 0; nt < 2; ++nt) {
      fragh k0, k1;
      const int key = j0 + nt * 16 + la;
#pragma unroll
      for (int jj = 0; jj < 4; ++jj) {
        k0.i4[jj] = Kb[(size_t)(quad * 4 + jj) * N_ + key];
        k1.i4[jj] = Kb[(size_t)(16 + quad * 4 + jj) * N_ + key];
      }
      f32x4 z = f32x4{0.f, 0.f, 0.f, 0.f};
      z = __builtin_amdgcn_mfma_f32_16x16x32_f16(aq[0].h8, k0.h8, z, 0, 0, 0);
      s[nt] = __builtin_amdgcn_mfma_f32_16x16x32_f16(aq[1].h8, k1.h8, z, 0, 0, 0);
    }
    float alpha[4];
#pragma unroll
    for (int r = 0; r < 4; ++r) {
      float t = fmaxf(s[0][r], s[1][r]);
      t = fmaxf(t, __shfl_xor(t, 1));
      t = fmaxf(t, __shfl_xor(t, 2));
      t = fmaxf(t, __shfl_xor(t, 4));
      t = fmaxf(t, __shfl_xor(t, 8));
      float mnew = fmaxf(mrun[r], t);
      alpha[r] = __expf(mrun[r] - mnew);
      float p0 = __expf(s[0][r] - mnew);
      float p1 = __expf(s[1][r] - mnew);
      s[0][r] = p0; s[1][r] = p1;
      float ps = p0 + p1;
      ps += __shfl_xor(ps, 1);
      ps += __shfl_xor(ps, 2);
      ps += __shfl_xor(ps, 4);
      ps += __shfl_xor(ps, 8);
      lrun[r] = lrun[r] * alpha[r] + ps;
      mrun[r] = mnew;
    }
#pragma unroll
    for (int nt = 0; nt < 2; ++nt)
#pragma unroll
      for (int r = 0; r < 4; ++r)
        myP[(quad * 4 + r) * 36 + nt * 16 + la] = s[nt][r];
    __asm__ __volatile__("s_waitcnt lgkmcnt(0)" ::: "memory");
    fragh pa;
    {
      const f32x4* pr = (const f32x4*)&myP[la * 36 + quad * 8];
      f32x4 p0 = pr[0], p1 = pr[1];
      pa.i4[0] = pkh(p0[0], p0[1]);
      pa.i4[1] = pkh(p0[2], p0[3]);
      pa.i4[2] = pkh(p1[0], p1[1]);
      pa.i4[3] = pkh(p1[2], p1[3]);
    }
#pragma unroll
    for (int mt = 0; mt < 4; ++mt)
#pragma unroll
      for (int r = 0; r < 4; ++r) o[mt][r] *= alpha[r];
#pragma unroll
    for (int mt = 0; mt < 4; ++mt) {
      const int4 vv = *(const int4*)&Vb[(size_t)(mt * 16 + la) * 2048 + (j0 >> 1) + quad * 4];
      fragh vb;
      vb.i4[0] = vv.x; vb.i4[1] = vv.y; vb.i4[2] = vv.z; vb.i4[3] = vv.w;
      o[mt] = __builtin_amdgcn_mfma_f32_16x16x32_f16(pa.h8, vb.h8, o[mt], 0, 0, 0);
    }
  }

  __syncthreads();
  if (la == 0) {
#pragma unroll
    for (int r = 0; r < 4; ++r) {
      smu.e.M[wid][quad * 4 + r] = mrun[r];
      smu.e.L[wid][quad * 4 + r] = lrun[r];
    }
  }
#pragma unroll
  for (int mt = 0; mt < 4; ++mt)
#pragma unroll
    for (int r = 0; r < 4; ++r) smu.e.O[wid][quad * 4 + r][mt * 16 + la] = o[mt][r];
  __syncthreads();

#pragma unroll
  for (int t = 0; t < 4; ++t) {
    int oidx = t * 256 + tid;
    int m = oidx >> 4;
    int q = oidx & 15;
    float m0 = fmaxf(fmaxf(smu.e.M[0][q], smu.e.M[1][q]),
                     fmaxf(smu.e.M[2][q], smu.e.M[3][q]));
    float num = 0.f, den = 0.f;
#pragma unroll
    for (int w = 0; w < 4; ++w) {
      float wgt = __expf(smu.e.M[w][q] - m0);
      num += wgt * smu.e.O[w][q][m];
      den += wgt * smu.e.L[w][q];
    }
    fout[((size_t)b * 64 + m) * N_ + qbase + q] = num / den;
  }
}

// ---------------- f_up conv (K=64, O=512): SGEMM tiling ----------------------------
__global__ __launch_bounds__(256) void convup_k(const float* __restrict__ fout,
                                                const float* __restrict__ wu,
                                                float* __restrict__ u,
                                                float* __restrict__ stats) {
  const int t = threadIdx.x;
  const int slice = blockIdx.x;
  const int b = slice >> 5;
  const int n0 = (slice & 31) * 128;
  const int o0 = blockIdx.y * 64;

  __shared__ float sA[32][132];
  __shared__ float sW[32][72];

  const int to = (t >> 5) * 8;
  const int tn = (t & 31) * 4;
  float acc[8][4];
#pragma unroll
  for (int i = 0; i < 8; ++i)
#pragma unroll
    for (int j = 0; j < 4; ++j) acc[i][j] = 0.f;

  const float* Ab = fout + (size_t)b * 64 * N_ + n0;
#pragma unroll 1
  for (int k0 = 0; k0 < 64; k0 += 32) {
    __syncthreads();
#pragma unroll
    for (int i = 0; i < 4; ++i) {
      int row = i * 8 + (t >> 5);
      float4 v = *(const float4*)&Ab[(size_t)(k0 + row) * N_ + tn];
      *(float4*)&sA[row][tn] = v;
    }
    {
      int o = t >> 2, kk = (t & 3) * 8;
      float4 w0 = *(const float4*)&wu[(size_t)(o0 + o) * 64 + k0 + kk];
      float4 w1 = *(const float4*)&wu[(size_t)(o0 + o) * 64 + k0 + kk + 4];
      sW[kk + 0][o] = w0.x; sW[kk + 1][o] = w0.y;
      sW[kk + 2][o] = w0.z; sW[kk + 3][o] = w0.w;
      sW[kk + 4][o] = w1.x; sW[kk + 5][o] = w1.y;
      sW[kk + 6][o] = w1.z; sW[kk + 7][o] = w1.w;
    }
    __syncthreads();
#pragma unroll
    for (int k = 0; k < 32; ++k) {
      float4 a = *(const float4*)&sA[k][tn];
      float4 w0 = *(const float4*)&sW[k][to];
      float4 w1 = *(const float4*)&sW[k][to + 4];
      float wv[8] = {w0.x, w0.y, w0.z, w0.w, w1.x, w1.y, w1.z, w1.w};
      float av[4] = {a.x, a.y, a.z, a.w};
#pragma unroll
      for (int i = 0; i < 8; ++i)
#pragma unroll
        for (int j = 0; j < 4; ++j) acc[i][j] += wv[i] * av[j];
    }
  }
  float* Cb = u + ((size_t)b * 512 + o0) * N_ + n0;
#pragma unroll
  for (int i = 0; i < 8; ++i) {
    float4 v = {acc[i][0], acc[i][1], acc[i][2], acc[i][3]};
    *(float4*)&Cb[(size_t)(to + i) * N_ + tn] = v;
  }
#pragma unroll
  for (int i = 0; i < 8; ++i) {
    float s = acc[i][0] + acc[i][1] + acc[i][2] + acc[i][3];
    float q = acc[i][0] * acc[i][0] + acc[i][1] * acc[i][1] +
              acc[i][2] * acc[i][2] + acc[i][3] * acc[i][3];
#pragma unroll
    for (int d = 1; d < 32; d <<= 1) { s += __shfl_xor(s, d); q += __shfl_xor(q, d); }
    if ((t & 31) == 0) {
      atomicAdd(&stats[768 + o0 + to + i], s);
      atomicAdd(&stats[1280 + o0 + to + i], q);
    }
  }
}

// ---------------- residual + final BN ----------------------------------------------
__global__ __launch_bounds__(256) void final_k(const float* __restrict__ x,
                                               const float* __restrict__ u,
                                               const float* __restrict__ gu,
                                               const float* __restrict__ bu,
                                               const float* __restrict__ stats,
                                               float* __restrict__ out) {
  size_t idx = (size_t)blockIdx.x * 256 + threadIdx.x;
  int c = (int)((idx >> 12) & 511);
  float mean = stats[768 + c] * (1.f / CNT);
  float var = stats[1280 + c] * (1.f / CNT) - mean * mean;
  float r = rsqrtf(var + 1e-5f);
  float s = gu[c] * r;
  float sh = bu[c] - mean * s;
  out[idx] = x[idx] + u[idx] * s + sh;
}

extern "C" void kernel_launch(void* const* d_in, const int* in_sizes, int n_in,
                              void* d_out, int out_size, void* d_ws, size_t ws_size,
                              hipStream_t stream) {
  const float* x = (const float*)d_in[0];
  const float* y = (const float*)d_in[1];
  const float* ws1 = (const float*)d_in[2];
  const float* gs1 = (const float*)d_in[3];
  const float* bs1 = (const float*)d_in[4];
  const float* ws2 = (const float*)d_in[5];
  const float* gs2 = (const float*)d_in[6];
  const float* bs2 = (const float*)d_in[7];
  const float* wx1 = (const float*)d_in[8];
  const float* gx1 = (const float*)d_in[9];
  const float* bx1 = (const float*)d_in[10];
  const float* wx2 = (const float*)d_in[11];
  const float* gx2 = (const float*)d_in[12];
  const float* bx2 = (const float*)d_in[13];
  const float* wy1 = (const float*)d_in[14];
  const float* gy1 = (const float*)d_in[15];
  const float* by1 = (const float*)d_in[16];
  const float* wy2 = (const float*)d_in[17];
  const float* gy2 = (const float*)d_in[18];
  const float* by2 = (const float*)d_in[19];
  const float* wu = (const float*)d_in[20];
  const float* gu = (const float*)d_in[21];
  const float* bu = (const float*)d_in[22];
  float* out = (float*)d_out;

  float* w = (float*)d_ws;
  const size_t M1 = 1048576;
  float* z1s = w + 0 * M1;
  float* z1x = w + 1 * M1;
  float* z1y = w + 2 * M1;
  float* z2s = w + 3 * M1;
  float* z2x = w + 4 * M1;
  float* z2y = w + 5 * M1;
  float* fout = w + 6 * M1;
  float* u = w + 7 * M1;  // [4][512][4096] = 8 M floats
  int* Qh = (int*)(w + 15 * M1);
  int* Kh = Qh + 524288;
  int* Vp = Kh + 524288;
  float* stats = (float*)(Vp + 524288);

  hipMemsetAsync(stats, 0, 1792 * sizeof(float), stream);

  conv1_k<<<dim3(128, 3), dim3(256), 0, stream>>>(x, y, ws1, wx1, wy1, z1s, z1x,
                                                  z1y, stats);
  conv2_k<<<dim3(128, 3), dim3(256), 0, stream>>>(
      z1s, z1x, z1y, ws2, wx2, wy2, gs1, bs1, gx1, bx1, gy1, by1, z2s, z2x, z2y,
      stats);
  pack_k<<<dim3(2048, 1, 3), dim3(256), 0, stream>>>(z2s, z2x, z2y, gs2, bs2, gx2,
                                                     bx2, gy2, by2, Qh, Kh, Vp,
                                                     stats);
  attn_k<<<dim3(1024), dim3(256), 0, stream>>>(Qh, Kh, Vp, fout);
  convup_k<<<dim3(128, 8), dim3(256), 0, stream>>>(fout, wu, u, stats);
  final_k<<<dim3(32768), dim3(256), 0, stream>>>(x, u, gu, bu, stats, out);
}